// Round 1
// baseline (322.259 us; speedup 1.0000x reference)
//
#include <hip/hip_runtime.h>

// AttentionSampling: out[b,s,:] = q[b,s,:] + sum_f dot(LN(q)[b,s,:], LN(k)[b,4s+f,:]) * LN(v)[b,4s+f,:]
// B=4, Sq=2048, Skv=8192, D=1024, fp32.
//
// R5: the R1-R4 plateau (~120us/dispatch, all pipes <40%) was barrier-drain
// serialization: every __syncthreads() emits s_waitcnt vmcnt(0), so each row was
// {burst 36KB -> full drain -> 5-barrier reduce chain with 0 bytes in flight}.
// Fix: persistent blocks (512 = 2/CU), double-buffered LDS staging, counted
// s_waitcnt vmcnt(9) + raw s_barrier for the "tile ready" sync (next row's 36KB
// stays in flight across the whole compute chain), and lgkmcnt-only barriers for
// the cross-wave reductions. Compute math is bit-identical to R4.
//
// vmcnt ledger (per wave, 9 global_load_lds per row-group, store counts on gfx9):
//   iter i issues S(i+1):9 first, then waits vmcnt(9) -> drains S(i) (and any
//   older store), leaves exactly S(i+1) in flight. Last iter waits vmcnt(0).

constexpr int D     = 1024;
constexpr int BLOCK = 256;
constexpr int NW    = BLOCK / 64;
constexpr int NR    = 16;            // rows per persistent block: 8192/512
constexpr float EPS = 1e-5f;

#define GLOBAL_AS const __attribute__((address_space(1))) void*
#define LDS_AS __attribute__((address_space(3))) void*

template<int CTRL>
__device__ __forceinline__ float dpp_add(float x) {
    int xi = __builtin_bit_cast(int, x);
    int yi = __builtin_amdgcn_update_dpp(0, xi, CTRL, 0xF, 0xF, true);
    return x + __builtin_bit_cast(float, yi);
}

// Full wave64 sum on the VALU pipe; broadcast via readlane (SGPR).
__device__ __forceinline__ float wave_sum(float x) {
    x = dpp_add<0x111>(x);   // row_shr:1
    x = dpp_add<0x112>(x);   // row_shr:2
    x = dpp_add<0x114>(x);   // row_shr:4
    x = dpp_add<0x118>(x);   // row_shr:8
    x = dpp_add<0x142>(x);   // row_bcast:15
    x = dpp_add<0x143>(x);   // row_bcast:31 -> lane 63 holds wave sum
    return __builtin_bit_cast(float, __builtin_amdgcn_readlane(__builtin_bit_cast(int, x), 63));
}

// LDS-only barrier: drains lgkmcnt (ds ops) but leaves the global_load_lds
// queue (vmcnt) untouched -- this is the whole point of R5.
__device__ __forceinline__ void bar_lds() {
    asm volatile("s_waitcnt lgkmcnt(0)" ::: "memory");
    __builtin_amdgcn_s_barrier();
    asm volatile("" ::: "memory");   // no LDS reads hoisted above the barrier
}

// Block-wide sum of N per-thread values, broadcast to all threads.
template <int N, bool TRAIL>
__device__ __forceinline__ void block_reduce(float* vals, float* s_buf,
                                             int lane, int wid) {
#pragma unroll
    for (int i = 0; i < N; i++) {
        float x = wave_sum(vals[i]);
        if (lane == 0) s_buf[wid * N + i] = x;
    }
    bar_lds();
#pragma unroll
    for (int i = 0; i < N; i++) {
        float t = 0.f;
#pragma unroll
        for (int w = 0; w < NW; w++) t += s_buf[w * N + i];
        vals[i] = t;
    }
    if (TRAIL) bar_lds();   // protect s_buf reuse by the NEXT reduce this iter
    // (no TRAIL on the last reduce of a row: subsumed by next ready-barrier)
}

// Stage one row-group (q row 4KB + 4 k rows 16KB + 4 v rows 16KB) into LDS.
// Exactly 9 global_load_lds (width 16) per wave -- fire-and-forget, 0 dest VGPRs.
// buf layout: [0..1023]=q, [1024..5119]=k rows 0..3, [5120..9215]=v rows 0..3.
__device__ __forceinline__ void stage_row(const float* __restrict__ q,
                                          const float* __restrict__ k,
                                          const float* __restrict__ v,
                                          long row, float* buf, int wid, int lane) {
    const int lo = lane * 4;
    __builtin_amdgcn_global_load_lds((GLOBAL_AS)(q + row * D + wid * 256 + lo),
                                     (LDS_AS)(buf + wid * 256), 16, 0, 0);
    const float* kb = k + row * (4L * D) + wid * 256 + lo;
    const float* vb = v + row * (4L * D) + wid * 256 + lo;
    float* dk = buf + 1024 + wid * 256;
    float* dv = buf + 5120 + wid * 256;
#pragma unroll
    for (int i = 0; i < 4; i++)
        __builtin_amdgcn_global_load_lds((GLOBAL_AS)(kb + i * 1024),
                                         (LDS_AS)(dk + i * 1024), 16, 0, 0);
#pragma unroll
    for (int i = 0; i < 4; i++)
        __builtin_amdgcn_global_load_lds((GLOBAL_AS)(vb + i * 1024),
                                         (LDS_AS)(dv + i * 1024), 16, 0, 0);
}

// Identical math to R4 (proven numerics), q now read from LDS.
__device__ __forceinline__ void compute_row(const float* buf, float* s_buf,
                                            const float4 wv, const float4 bv,
                                            float* __restrict__ outp,
                                            int lane, int wid, int d0) {
    const float4 qv = *(const float4*)(buf + d0);
    float red[18];
    red[0] = qv.x + qv.y + qv.z + qv.w;
    red[1] = qv.x * qv.x + qv.y * qv.y + qv.z * qv.z + qv.w * qv.w;
    float4 kv4[4], vv4[4];
#pragma unroll
    for (int f = 0; f < 4; f++) {
        kv4[f] = *(const float4*)(buf + 1024 + f * D + d0);
        vv4[f] = *(const float4*)(buf + 5120 + f * D + d0);
        red[2 + 2 * f]  = kv4[f].x + kv4[f].y + kv4[f].z + kv4[f].w;
        red[3 + 2 * f]  = kv4[f].x * kv4[f].x + kv4[f].y * kv4[f].y
                        + kv4[f].z * kv4[f].z + kv4[f].w * kv4[f].w;
        red[10 + 2 * f] = vv4[f].x + vv4[f].y + vv4[f].z + vv4[f].w;
        red[11 + 2 * f] = vv4[f].x * vv4[f].x + vv4[f].y * vv4[f].y
                        + vv4[f].z * vv4[f].z + vv4[f].w * vv4[f].w;
    }
    block_reduce<18, true>(red, s_buf, lane, wid);

    const float invD = 1.0f / (float)D;
    const float mu_q = red[0] * invD;
    const float rs_q = rsqrtf(fmaf(-mu_q, mu_q, red[1] * invD) + EPS);
    float mu_k[4], rs_k[4], mu_v[4], rs_v[4];
#pragma unroll
    for (int f = 0; f < 4; f++) {
        mu_k[f] = red[2 + 2 * f] * invD;
        rs_k[f] = rsqrtf(fmaf(-mu_k[f], mu_k[f], red[3 + 2 * f] * invD) + EPS);
        mu_v[f] = red[10 + 2 * f] * invD;
        rs_v[f] = rsqrtf(fmaf(-mu_v[f], mu_v[f], red[11 + 2 * f] * invD) + EPS);
    }

    float4 qn;
    qn.x = fmaf((qv.x - mu_q) * rs_q, wv.x, bv.x);
    qn.y = fmaf((qv.y - mu_q) * rs_q, wv.y, bv.y);
    qn.z = fmaf((qv.z - mu_q) * rs_q, wv.z, bv.z);
    qn.w = fmaf((qv.w - mu_q) * rs_q, wv.w, bv.w);
    float dp[4];
#pragma unroll
    for (int f = 0; f < 4; f++) {
        float4 kn;
        kn.x = fmaf((kv4[f].x - mu_k[f]) * rs_k[f], wv.x, bv.x);
        kn.y = fmaf((kv4[f].y - mu_k[f]) * rs_k[f], wv.y, bv.y);
        kn.z = fmaf((kv4[f].z - mu_k[f]) * rs_k[f], wv.z, bv.z);
        kn.w = fmaf((kv4[f].w - mu_k[f]) * rs_k[f], wv.w, bv.w);
        dp[f] = qn.x * kn.x + qn.y * kn.y + qn.z * kn.z + qn.w * kn.w;
    }
    block_reduce<4, false>(dp, s_buf, lane, wid);

    float4 acc = qv;
#pragma unroll
    for (int f = 0; f < 4; f++) {
        const float av = rs_v[f], cv = -mu_v[f] * rs_v[f], dpf = dp[f];
#define ACCO(m) { \
        float t  = fmaf(av, vv4[f].m, cv); \
        float vn = fmaf(t, wv.m, bv.m); \
        acc.m = fmaf(dpf, vn, acc.m); }
        ACCO(x) ACCO(y) ACCO(z) ACCO(w)
#undef ACCO
    }
    *(float4*)(outp + d0) = acc;
}

__global__ __launch_bounds__(BLOCK, 2) void attn_ds_kernel(
    const float* __restrict__ q,    // [B*Sq, D]
    const float* __restrict__ k,    // [B*Sq*4, D]
    const float* __restrict__ v,    // [B*Sq*4, D]
    const float* __restrict__ lw,   // [D]
    const float* __restrict__ lb,   // [D]
    float* __restrict__ out)        // [B*Sq, D]
{
    __shared__ float buf0[9 * 1024];     // 36 KB: q + 4k + 4v rows
    __shared__ float buf1[9 * 1024];     // double buffer
    __shared__ float s_buf[NW * 18];

    const int tid  = threadIdx.x;
    const int lane = tid & 63;
    const int wid  = tid >> 6;
    const int d0   = tid * 4;
    const long r0  = (long)blockIdx.x * NR;

    // w/b loaded once; force their vmcnt wait to land HERE (pre-pipeline) so the
    // compiler's waitcnt pass never drains the staging queue inside the loop.
    const float4 wv = *(const float4*)(lw + d0);
    const float4 bv = *(const float4*)(lb + d0);
    asm volatile("" :: "v"(wv.x), "v"(wv.y), "v"(wv.z), "v"(wv.w),
                       "v"(bv.x), "v"(bv.y), "v"(bv.z), "v"(bv.w));

    stage_row(q, k, v, r0, buf0, wid, lane);          // S(0)

#pragma unroll 1
    for (int i = 0; i < NR; i += 2) {
        // ---- even row: compute buf0, prefetch into buf1 ----
        stage_row(q, k, v, r0 + i + 1, buf1, wid, lane);          // S(i+1)
        asm volatile("s_waitcnt vmcnt(9)" ::: "memory");          // S(i) done; S(i+1) in flight
        __builtin_amdgcn_s_barrier();                             // all waves' S(i) visible
        asm volatile("" ::: "memory");
        compute_row(buf0, s_buf, wv, bv, out + (r0 + i) * D, lane, wid, d0);

        // ---- odd row: compute buf1, prefetch into buf0 ----
        if (i + 2 < NR) {
            stage_row(q, k, v, r0 + i + 2, buf0, wid, lane);      // S(i+2)
            asm volatile("s_waitcnt vmcnt(9)" ::: "memory");      // S(i+1) done
        } else {
            asm volatile("s_waitcnt vmcnt(0)" ::: "memory");      // final drain
        }
        __builtin_amdgcn_s_barrier();
        asm volatile("" ::: "memory");
        compute_row(buf1, s_buf, wv, bv, out + (r0 + i + 1) * D, lane, wid, d0);
    }
}

extern "C" void kernel_launch(void* const* d_in, const int* in_sizes, int n_in,
                              void* d_out, int out_size, void* d_ws, size_t ws_size,
                              hipStream_t stream) {
    const float* q  = (const float*)d_in[0];
    const float* k  = (const float*)d_in[1];
    const float* v  = (const float*)d_in[2];
    const float* lw = (const float*)d_in[3];
    const float* lb = (const float*)d_in[4];
    float* out = (float*)d_out;

    const int rows = in_sizes[0] / D;   // B*Sq = 8192
    const int grid = rows / NR;         // 512 blocks = 2 per CU, no tail
    attn_ds_kernel<<<dim3(grid), dim3(BLOCK), 0, stream>>>(q, k, v, lw, lb, out);
}

// Round 2
// 312.638 us; speedup vs baseline: 1.0308x; 1.0308x over previous
//
#include <hip/hip_runtime.h>

// AttentionSampling: out[b,s,:] = q[b,s,:] + sum_f dot(LN(q)[b,s,:], LN(k)[b,4s+f,:]) * LN(v)[b,4s+f,:]
// B=4, Sq=2048, Skv=8192, D=1024, fp32.
//
// R6: R4/R5 both capped at ~120us (~4 B/cy/CU) despite different LDS schedules ->
// the cap is the compiler-inserted vmcnt(0) drain before every LDS read of
// global_load_lds destinations + barrier convoy. Fix: remove LDS and barriers
// entirely. One wave per row (D=1024 = 64 lanes x 16 floats), everything in
// registers via plain global_load_dwordx4 (compiler emits fine-grained counted
// vmcnt for register loads), all reductions in-wave via DPP. dot(qn,kn) is
// algebraically expanded so k is single-pass (streamed through a 2-row window):
//   dp_f = rs_q*rs_k*(Sqkw2 - mu_k*Sqw2 - mu_q*Skw2_f + mu_q*mu_k*Sw2)
//        + rs_q*(Sqwb - mu_q*Swb) + rs_k*(Skwb_f - mu_k*Swb) + Sb2
// q,v stay resident for the epilogue. 36 independent loads in flight per wave,
// 8 waves/CU -> ~200KB outstanding/CU vs ~10KB needed for full HBM rate.

typedef float f32x4 __attribute__((ext_vector_type(4)));

constexpr int D     = 1024;
constexpr int BLOCK = 256;
constexpr int NW    = BLOCK / 64;   // waves per block
constexpr int NRW   = 4;            // rows per wave
constexpr float EPS = 1e-5f;

template<int CTRL>
__device__ __forceinline__ float dpp_add(float x) {
    int xi = __builtin_bit_cast(int, x);
    int yi = __builtin_amdgcn_update_dpp(0, xi, CTRL, 0xF, 0xF, true);
    return x + __builtin_bit_cast(float, yi);
}

// Full wave64 sum on the VALU pipe; broadcast via readlane (SGPR). No LDS, no barrier.
__device__ __forceinline__ float wave_sum(float x) {
    x = dpp_add<0x111>(x);   // row_shr:1
    x = dpp_add<0x112>(x);   // row_shr:2
    x = dpp_add<0x114>(x);   // row_shr:4
    x = dpp_add<0x118>(x);   // row_shr:8
    x = dpp_add<0x142>(x);   // row_bcast:15
    x = dpp_add<0x143>(x);   // row_bcast:31 -> lane 63 holds wave sum
    return __builtin_bit_cast(float, __builtin_amdgcn_readlane(__builtin_bit_cast(int, x), 63));
}

__device__ __forceinline__ f32x4 vadd(f32x4 a, f32x4 b) {
    f32x4 r;
#pragma unroll
    for (int j = 0; j < 4; j++) r[j] = a[j] + b[j];
    return r;
}
__device__ __forceinline__ f32x4 vmul(f32x4 a, f32x4 b) {
    f32x4 r;
#pragma unroll
    for (int j = 0; j < 4; j++) r[j] = a[j] * b[j];
    return r;
}
__device__ __forceinline__ f32x4 vfma(f32x4 a, f32x4 b, f32x4 c) {
    f32x4 r;
#pragma unroll
    for (int j = 0; j < 4; j++) r[j] = fmaf(a[j], b[j], c[j]);
    return r;
}
// r = a*s + c  (scalar s, scalar c)
__device__ __forceinline__ f32x4 vfma_ss(f32x4 a, float s, float c) {
    f32x4 r;
#pragma unroll
    for (int j = 0; j < 4; j++) r[j] = fmaf(a[j], s, c);
    return r;
}
// r = s*b + c  (scalar s, vector b, vector c)
__device__ __forceinline__ f32x4 vfma_sv(float s, f32x4 b, f32x4 c) {
    f32x4 r;
#pragma unroll
    for (int j = 0; j < 4; j++) r[j] = fmaf(s, b[j], c[j]);
    return r;
}
__device__ __forceinline__ float hsum(f32x4 a) { return (a[0] + a[1]) + (a[2] + a[3]); }

__global__ __launch_bounds__(BLOCK, 2) void attn_ds_kernel(
    const float* __restrict__ q,    // [rows, D]
    const float* __restrict__ k,    // [rows*4, D]
    const float* __restrict__ v,    // [rows*4, D]
    const float* __restrict__ lw,   // [D]
    const float* __restrict__ lb,   // [D]
    float* __restrict__ out,        // [rows, D]
    int rows)
{
    const int  tid  = threadIdx.x;
    const int  lane = tid & 63;
    const int  wid  = tid >> 6;
    const int  sl   = lane * 4;                    // element slot within each 256-chunk
    const long gw   = (long)blockIdx.x * NW + wid; // global wave id
    long r = gw * NRW;

    // ---- row-invariant: w,b resident (32 VGPRs) + their 3 reductions, once ----
    f32x4 wv[4], bv[4];
#pragma unroll
    for (int i = 0; i < 4; i++) {
        wv[i] = *(const f32x4*)(lw + i * 256 + sl);
        bv[i] = *(const f32x4*)(lb + i * 256 + sl);
    }
    f32x4 aw2 = {0.f, 0.f, 0.f, 0.f}, awb = {0.f, 0.f, 0.f, 0.f}, ab2 = {0.f, 0.f, 0.f, 0.f};
#pragma unroll
    for (int i = 0; i < 4; i++) {
        aw2 = vfma(wv[i], wv[i], aw2);
        awb = vfma(wv[i], bv[i], awb);
        ab2 = vfma(bv[i], bv[i], ab2);
    }
    const float Sw2 = wave_sum(hsum(aw2));
    const float Swb = wave_sum(hsum(awb));
    const float Sb2 = wave_sum(hsum(ab2));
    const float invD = 1.0f / (float)D;

#pragma unroll 1
    for (int rr = 0; rr < NRW; rr++, r++) {
        if (r >= rows) break;
        const float* qp = q + r * (long)D;
        const float* kp = k + r * (4L * D);
        const float* vp = v + r * (4L * D);

        // ---- issue the row's loads: q(4) + v(16) + k-half0(8) = 28 x dwordx4 ----
        f32x4 qv[4], vv[4][4], kw[2][4];
#pragma unroll
        for (int i = 0; i < 4; i++) qv[i] = *(const f32x4*)(qp + i * 256 + sl);
#pragma unroll
        for (int f = 0; f < 4; f++)
#pragma unroll
            for (int i = 0; i < 4; i++)
                vv[f][i] = *(const f32x4*)(vp + f * D + i * 256 + sl);
#pragma unroll
        for (int h = 0; h < 2; h++)
#pragma unroll
            for (int i = 0; i < 4; i++)
                kw[h][i] = *(const f32x4*)(kp + h * D + i * 256 + sl);

        // ---- q partials: Sq, Sqq, Sqw2=Sum q*w^2, Sqwb=Sum q*w*b ----
        f32x4 a0 = {0.f,0.f,0.f,0.f}, a1 = a0, a2 = a0, a3 = a0;
#pragma unroll
        for (int i = 0; i < 4; i++) {
            a0 = vadd(a0, qv[i]);
            a1 = vfma(qv[i], qv[i], a1);
            f32x4 t = vmul(qv[i], wv[i]);
            a2 = vfma(t, wv[i], a2);
            a3 = vfma(t, bv[i], a3);
        }
        float pSq = hsum(a0), pSqq = hsum(a1), pSqw2 = hsum(a2), pSqwb = hsum(a3);

        // ---- k partials for f=0,1 (window half 0) ----
        float pSk[4], pSkk[4], pSkw2[4], pSkwb[4], pA[4];
#pragma unroll
        for (int f = 0; f < 2; f++) {
            f32x4 s = {0.f,0.f,0.f,0.f}, ss = s, sw2a = s, swba = s, sA = s;
#pragma unroll
            for (int i = 0; i < 4; i++) {
                f32x4 kk = kw[f][i];
                s    = vadd(s, kk);
                ss   = vfma(kk, kk, ss);
                f32x4 t = vmul(kk, wv[i]);
                sw2a = vfma(t, wv[i], sw2a);
                swba = vfma(t, bv[i], swba);
                f32x4 u = vmul(qv[i], wv[i]);
                sA   = vfma(t, u, sA);
            }
            pSk[f] = hsum(s); pSkk[f] = hsum(ss);
            pSkw2[f] = hsum(sw2a); pSkwb[f] = hsum(swba); pA[f] = hsum(sA);
        }

        // ---- issue k-half1 loads (f=2,3), overlap with v partials ----
#pragma unroll
        for (int h = 0; h < 2; h++)
#pragma unroll
            for (int i = 0; i < 4; i++)
                kw[h][i] = *(const f32x4*)(kp + (2 + h) * D + i * 256 + sl);

        // ---- v partials: Sv_f, Svv_f ----
        float pSv[4], pSvv[4];
#pragma unroll
        for (int f = 0; f < 4; f++) {
            f32x4 s = {0.f,0.f,0.f,0.f}, ss = s;
#pragma unroll
            for (int i = 0; i < 4; i++) {
                s  = vadd(s, vv[f][i]);
                ss = vfma(vv[f][i], vv[f][i], ss);
            }
            pSv[f] = hsum(s); pSvv[f] = hsum(ss);
        }

        // ---- k partials for f=2,3 ----
#pragma unroll
        for (int f = 2; f < 4; f++) {
            f32x4 s = {0.f,0.f,0.f,0.f}, ss = s, sw2a = s, swba = s, sA = s;
#pragma unroll
            for (int i = 0; i < 4; i++) {
                f32x4 kk = kw[f - 2][i];
                s    = vadd(s, kk);
                ss   = vfma(kk, kk, ss);
                f32x4 t = vmul(kk, wv[i]);
                sw2a = vfma(t, wv[i], sw2a);
                swba = vfma(t, bv[i], swba);
                f32x4 u = vmul(qv[i], wv[i]);
                sA   = vfma(t, u, sA);
            }
            pSk[f] = hsum(s); pSkk[f] = hsum(ss);
            pSkw2[f] = hsum(sw2a); pSkwb[f] = hsum(swba); pA[f] = hsum(sA);
        }

        // ---- one round of 32 in-wave reductions (DPP, no barrier) ----
        const float Sq   = wave_sum(pSq);
        const float Sqq  = wave_sum(pSqq);
        const float Sqw2 = wave_sum(pSqw2);
        const float Sqwb = wave_sum(pSqwb);
        float Sk[4], Skk[4], Skw2[4], Skwb[4], A[4], Sv[4], Svv[4];
#pragma unroll
        for (int f = 0; f < 4; f++) {
            Sk[f]   = wave_sum(pSk[f]);
            Skk[f]  = wave_sum(pSkk[f]);
            Skw2[f] = wave_sum(pSkw2[f]);
            Skwb[f] = wave_sum(pSkwb[f]);
            A[f]    = wave_sum(pA[f]);
            Sv[f]   = wave_sum(pSv[f]);
            Svv[f]  = wave_sum(pSvv[f]);
        }

        // ---- scalar stats + expanded dot(qn, kn_f) ----
        const float mu_q = Sq * invD;
        const float rs_q = rsqrtf(fmaf(-mu_q, mu_q, Sqq * invD) + EPS);
        const float qlin = rs_q * (Sqwb - mu_q * Swb);   // rs_q * Sum (q-mu_q) w b
        float dp[4], rs_v[4], cv[4];
#pragma unroll
        for (int f = 0; f < 4; f++) {
            const float mu_k = Sk[f] * invD;
            const float rs_k = rsqrtf(fmaf(-mu_k, mu_k, Skk[f] * invD) + EPS);
            const float mu_v = Sv[f] * invD;
            const float rv   = rsqrtf(fmaf(-mu_v, mu_v, Svv[f] * invD) + EPS);
            const float cross = A[f] - mu_k * Sqw2 - mu_q * Skw2[f] + mu_q * mu_k * Sw2;
            dp[f] = rs_q * rs_k * cross + qlin + rs_k * (Skwb[f] - mu_k * Swb) + Sb2;
            rs_v[f] = rv;
            cv[f]   = -mu_v * rv;
        }

        // ---- epilogue from resident q,v: out = q + sum_f dp_f * LN(v_f) ----
#pragma unroll
        for (int i = 0; i < 4; i++) {
            f32x4 acc = qv[i];
#pragma unroll
            for (int f = 0; f < 4; f++) {
                f32x4 t  = vfma_ss(vv[f][i], rs_v[f], cv[f]);  // (v - mu_v)*rs_v
                f32x4 vn = vfma(t, wv[i], bv[i]);              // * w + b
                acc = vfma_sv(dp[f], vn, acc);                 // += dp * vn
            }
            *(f32x4*)(out + r * (long)D + i * 256 + sl) = acc;
        }
    }
}

extern "C" void kernel_launch(void* const* d_in, const int* in_sizes, int n_in,
                              void* d_out, int out_size, void* d_ws, size_t ws_size,
                              hipStream_t stream) {
    const float* q  = (const float*)d_in[0];
    const float* k  = (const float*)d_in[1];
    const float* v  = (const float*)d_in[2];
    const float* lw = (const float*)d_in[3];
    const float* lb = (const float*)d_in[4];
    float* out = (float*)d_out;

    const int rows = in_sizes[0] / D;                 // B*Sq = 8192
    const int grid = (rows + NW * NRW - 1) / (NW * NRW);  // 8192/16 = 512 = 2 blocks/CU
    attn_ds_kernel<<<dim3(grid), dim3(BLOCK), 0, stream>>>(q, k, v, lw, lb, out, rows);
}